// Round 18
// baseline (298.069 us; speedup 1.0000x reference)
//
#include <hip/hip_runtime.h>

// Padded layouts (halos zero):
//   fp32 [N][C][30][32]        : adder OUTPUTS (t2/t5)
//   u32  [N][64][30][32]       : adder INPUTS (t1/t4), packed u16 ci-pairs,
//                                q = rn((v+8)*4096)
//   bf16 [n][yp30][kc4][xp32][ci32] : MFMA inputs (x, t3) -- k-block-minor so
//                                     every wave fragment load is 1KB contiguous
#define PADH 30
#define PADW 32
#define CSTR (PADH*PADW)            // 960 elems per channel(-pair)
#define NIMG 32
#define NCH  128
#define HW   28
#define PBUF ((size_t)NIMG*NCH*CSTR)   // 3,932,160
#define WREL (128*128*9)               // 147456 weights per tensor
#define WPACK (WREL/2)                 // 73728 packed u32 per adder tensor

#define QS16   4096.0f
#define QINV16 (-2.44140625e-04f)      // -1/4096 (adder output is negated sum)
#define QZERO16 0x80008000u            // packed pair of rn(8*4096)=32768

typedef __attribute__((ext_vector_type(8))) short bf16x8;
typedef __attribute__((ext_vector_type(4))) float f32x4;
typedef __attribute__((ext_vector_type(4))) unsigned u32x4;
// Constant-address-space view: block-uniform address -> compiler emits s_load
// into SGPRs (scalar pipe), not VMEM/LDS.
typedef __attribute__((address_space(4))) const u32x4 cu32x4;

__device__ __forceinline__ unsigned short f2bf(float f) {   // RNE
  unsigned u = __float_as_uint(f);
  return (unsigned short)((u + 0x7FFFu + ((u >> 16) & 1u)) >> 16);
}

// ---------------------------------------------------------------------------
// Adder weights -> [cog32][cipair(64)][tap(9)][co4] u32 packed u16 pairs.
__global__ __launch_bounds__(256) void prep_adder(
    const float* __restrict__ a1, const float* __restrict__ a2,
    unsigned* __restrict__ dst) {
  int gid = blockIdx.x * 256 + threadIdx.x;          // 2*73728 threads
  int t = gid / WPACK, r = gid % WPACK;
  const float* src = t ? a2 : a1;
  int co = r / 576;                                  // 64 pairs * 9 taps
  int rem = r % 576;
  int pair = rem / 9, tap = rem % 9;
  float v0 = src[co * 1152 + (2 * pair) * 9 + tap];
  float v1 = src[co * 1152 + (2 * pair + 1) * 9 + tap];
  unsigned q0 = __float2uint_rn((v0 + 8.0f) * QS16);
  unsigned q1 = __float2uint_rn((v1 + 8.0f) * QS16);
  int cog = co >> 2, j = co & 3;
  dst[(size_t)t * WPACK + (((cog * 64 + pair) * 9 + tap) << 2) + j] = q0 | (q1 << 16);
}

// Shift weights: quantize sign*2^round(log2|w|) (zero < 0.005), exact in bf16.
// Layout [cog8][tap9][kc4][co16][ci32]: wave A-frag = 1KB contiguous.
__global__ __launch_bounds__(256) void prep_shift(
    const float* __restrict__ s1, const float* __restrict__ s2,
    unsigned short* __restrict__ dst) {
  int gid = blockIdx.x * 256 + threadIdx.x;          // 2*147456 threads
  int t = gid / WREL, r = gid % WREL;
  float v = (t ? s2 : s1)[r];
  float aw = fabsf(v);
  if (aw < 0.005f) {
    v = 0.0f;
  } else {
    int e; float m = frexpf(aw, &e);
    int k = (m >= 0.70710678f) ? e : e - 1;          // round(log2 aw)
    v = ldexpf(copysignf(1.0f, v), k);               // exact power of two
  }
  int co = r / 1152, rem = r % 1152;
  int ci = rem / 9, tap = rem % 9;
  int cog = co >> 4, cop = co & 15;
  dst[(size_t)t * WREL +
      ((((size_t)(cog * 9 + tap) * 4 + (ci >> 5)) * 16 + cop) * 32 + (ci & 31))] = f2bf(v);
}

// ---------------------------------------------------------------------------
// x (compact NCHW fp32) -> bf16 padded [n][yp][kc4][xp32][ci32].
__global__ __launch_bounds__(256) void pad_cl(
    const float* __restrict__ x, unsigned short* __restrict__ o) {
  __shared__ unsigned short tile[32 * 130];
  int n = blockIdx.x / PADH, yp = blockIdx.x % PADH;
  int tid = threadIdx.x;
  bool rowok = (yp >= 1 && yp <= HW);
#pragma unroll
  for (int it = 0; it < 16; ++it) {
    int idx = it * 256 + tid;                        // xp fast -> coalesced read
    int ci = idx >> 5, xp = idx & 31;
    float v = 0.0f;
    if (rowok && xp >= 1 && xp <= HW)
      v = x[(size_t)(n * NCH + ci) * (HW * HW) + (yp - 1) * HW + (xp - 1)];
    tile[xp * 130 + ci] = f2bf(v);
  }
  __syncthreads();
  unsigned int* ob = (unsigned int*)(o + (size_t)(n * PADH + yp) * 4096);
#pragma unroll
  for (int it = 0; it < 8; ++it) {
    int uidx = it * 256 + tid;                       // [kc4][xp32][cp16] linear
    int kc = uidx >> 9, xp = (uidx >> 4) & 31, cp = uidx & 15;
    int ci = kc * 32 + 2 * cp;
    ob[uidx] = *(const unsigned int*)&tile[xp * 130 + ci];
  }
}

// t2 (fp32 padded) -> BN+ReLU -> bf16 padded [n][yp][kc4][xp32][ci32].
__global__ __launch_bounds__(256) void bn_apply_relu_cl(
    const float* __restrict__ t, const float* __restrict__ sb,
    unsigned short* __restrict__ o) {
  __shared__ unsigned short tile[32 * 130];
  int n = blockIdx.x / PADH, yp = blockIdx.x % PADH;
  int tid = threadIdx.x;
  bool rowok = (yp >= 1 && yp <= HW);
#pragma unroll
  for (int it = 0; it < 16; ++it) {
    int idx = it * 256 + tid;
    int ci = idx >> 5, xp = idx & 31;
    float v = 0.0f;
    if (rowok && xp >= 1 && xp <= HW) {
      float tv = t[((size_t)(n * NCH + ci) * PADH + yp) * PADW + xp];
      v = fmaxf(fmaf(tv, sb[ci], sb[NCH + ci]), 0.0f);
    }
    tile[xp * 130 + ci] = f2bf(v);
  }
  __syncthreads();
  unsigned int* ob = (unsigned int*)(o + (size_t)(n * PADH + yp) * 4096);
#pragma unroll
  for (int it = 0; it < 8; ++it) {
    int uidx = it * 256 + tid;
    int kc = uidx >> 9, xp = (uidx >> 4) & 31, cp = uidx & 15;
    int ci = kc * 32 + 2 * cp;
    ob[uidx] = *(const unsigned int*)&tile[xp * 130 + ci];
  }
}

// Zero (quantized) halo cells of the packed u32 adder-input buffer.
__global__ __launch_bounds__(256) void zero_halo(unsigned* __restrict__ b) {
  int gid = blockIdx.x * 256 + threadIdx.x;          // 2048*120 threads
  int nc = gid / 120, i = gid % 120;                 // nc over N*64 pairs
  unsigned* p = b + (size_t)nc * CSTR;
  if (i < 64) {
    int row = (i < 32) ? 0 : (PADH - 1);
    p[row * PADW + (i & 31)] = QZERO16;
  } else {
    int i2 = i - 64;
    int row = 1 + (i2 >> 1);
    int col = (i2 & 1) ? (HW + 1) : 0;
    p[row * PADW + col] = QZERO16;
  }
}

// ---------------------------------------------------------------------------
// Shift conv on matrix cores. Block = 512 thr = 8 waves = ALL 8 co-tiles of
// one (n, pxt): shared input tile (32KB) staged in LDS once, re-used by all
// 8 waves. Wave tap-fragment read = contiguous 1KB LDS -> conflict-free.
__global__ __launch_bounds__(512) void shift_mfma(
    const unsigned short* __restrict__ in, const unsigned short* __restrict__ wq,
    unsigned* __restrict__ out) {
  __shared__ uint4 btile4[2048];                     // 32KB: 4 rows x 8KB
  char* btile = (char*)btile4;
  int bid = blockIdx.x;
  int vb = (bid & 7) * 196 + (bid >> 3);             // bijective (1568 = 8*196)
  int pxt = vb % 49;
  int n = vb / 49;
  int cot = threadIdx.x >> 6;                        // wave id = co-tile 0..7
  int lane = threadIdx.x & 63;
  int t = threadIdx.x;

  int px0 = pxt * 16;
  int y0 = px0 / HW;                                 // logical row of first px
#pragma unroll
  for (int it = 0; it < 4; ++it) {
    int rp = y0 + it; if (rp > 29) rp = 29;
    const uint4* src = (const uint4*)(in + (size_t)(n * PADH + rp) * 4096) + t;
    *(uint4*)(btile + it * 8192 + t * 16) = *src;
  }
  __syncthreads();

  int px = px0 + (lane & 15);
  int y = px / HW, x = px % HW;
  int iro = y - y0;                                  // 0 or 1
  int colb = (x + 1) * 64 + (lane >> 4) * 16;        // byte offset in row blk
  const unsigned short* wbase =
      wq + (size_t)cot * 18432 + (lane & 15) * 32 + (lane >> 4) * 8;

  f32x4 acc = {0.f, 0.f, 0.f, 0.f};
#pragma unroll
  for (int tap = 0; tap < 9; ++tap) {
    const int ky = tap / 3 - 1, kx = tap % 3 - 1;
    const char* lb = btile + (iro + ky + 1) * 8192 + colb + kx * 64;
    const unsigned short* wb = wbase + tap * 2048;
#pragma unroll
    for (int kc = 0; kc < 4; ++kc) {
      bf16x8 a = *(const bf16x8*)(wb + kc * 512);
      bf16x8 b = *(const bf16x8*)(lb + kc * 2048);
      acc = __builtin_amdgcn_mfma_f32_16x16x32_bf16(a, b, acc, 0, 0, 0);
    }
  }
  int coa = cot * 16 + (lane >> 4) * 4;              // 4 consecutive co
  unsigned q[4];
#pragma unroll
  for (int r = 0; r < 4; ++r) {
    float v = fminf(fmaxf(acc[r], -7.9f), 7.9f);     // ~8-sigma clamp
    q[r] = __float2uint_rn((v + 8.0f) * QS16);
  }
  int cp = coa >> 1;                                 // channel-pair index
  unsigned* ob = out + ((size_t)(n * 64 + cp) * PADH + (y + 1)) * PADW + (x + 1);
  ob[0] = q[0] | (q[1] << 16);
  ob[CSTR] = q[2] | (q[3] << 16);
}

// ---------------------------------------------------------------------------
// AdderNet conv, packed u16 SAD. v_sad_u16 measured half-rate (R17: VALU-busy
// time == 4cyc/SAD model exactly) -> raise per-wave SAD issue density instead
// of pipelining deeper: thread = 4px x 4co (144 SAD per 6 load instrs, 2x the
// old density). Block 128 thr; grid 1568 = 8*196 bijective XCD swizzle.
__device__ __forceinline__ void sad16_op(unsigned& acc, unsigned vin, unsigned w) {
  asm("v_sad_u16 %0, %1, %2, %0" : "+v"(acc) : "v"(vin), "s"(w));
}

// Rows y-1..y+1, padded cols x0..x0+5 (logical x0-1..x0+4). x0%4==0 ->
// uint4 at x0 is 16B-aligned, uint2 at x0+4 is 8B-aligned.
__device__ __forceinline__ void load_rows6(const unsigned* __restrict__ p,
                                           unsigned r[3][6]) {
#pragma unroll
  for (int ky = 0; ky < 3; ++ky) {
    uint4 a = *(const uint4*)(p + ky * PADW);
    uint2 b = *(const uint2*)(p + ky * PADW + 4);
    r[ky][0] = a.x; r[ky][1] = a.y; r[ky][2] = a.z; r[ky][3] = a.w;
    r[ky][4] = b.x; r[ky][5] = b.y;
  }
}

__device__ __forceinline__ void adder_ci4(const unsigned r[3][6],
                                          const u32x4 w[9],
                                          unsigned acc[4][4]) {
#pragma unroll
  for (int ky = 0; ky < 3; ++ky)
#pragma unroll
    for (int kx = 0; kx < 3; ++kx) {
      u32x4 wA = w[ky * 3 + kx];                     // SGPRs
#pragma unroll
      for (int p = 0; p < 4; ++p) {
        unsigned vv = r[ky][kx + p];
        sad16_op(acc[0][p], vv, wA.x);
        sad16_op(acc[1][p], vv, wA.y);
        sad16_op(acc[2][p], vv, wA.z);
        sad16_op(acc[3][p], vv, wA.w);
      }
    }
}

__global__ __launch_bounds__(128) void adder_conv(
    const unsigned* __restrict__ in, const unsigned* __restrict__ wr,
    float* __restrict__ out) {
  int bid = blockIdx.x;
  int v = (bid & 7) * 196 + (bid >> 3);              // XCD remap (1568 = 8*196)
  int cog = v & 31;                                  // 32 groups of 4 co
  int chunk = v >> 5;                                // 0..48
  int tid = threadIdx.x;

  int wi = chunk * 128 + tid;                        // 0..6271
  int xh = wi % 7;                                   // 7 groups of 4 px
  int r2 = wi / 7;
  int y = r2 % 28;
  int n = r2 / 28;
  int x0 = xh << 2;                                  // 0,4,...,24
  const unsigned* ib = in + (size_t)n * 64 * CSTR + y * PADW + x0;  // ci-pair 0
  cu32x4* w4 = (cu32x4*)(wr + (size_t)cog * 2304);   // [cipair][9 x u32x4]

  unsigned acc[4][4];
#pragma unroll
  for (int j = 0; j < 4; ++j)
#pragma unroll
    for (int p = 0; p < 4; ++p) acc[j][p] = 0u;

  u32x4 cw[9], nw[9];
#pragma unroll
  for (int t = 0; t < 9; ++t) cw[t] = w4[t];         // cp=0 weights
  unsigned ra[3][6], rb[3][6];
  load_rows6(ib, ra);

  for (int cp = 0; cp < 64; cp += 2) {
#pragma unroll
    for (int t = 0; t < 9; ++t) nw[t] = w4[(cp + 1) * 9 + t];   // prefetch cp+1
    load_rows6(ib + CSTR, rb);
    adder_ci4(ra, cw, acc);                          // compute cp
    if (cp + 2 < 64) {
#pragma unroll
      for (int t = 0; t < 9; ++t) cw[t] = w4[(cp + 2) * 9 + t]; // prefetch cp+2
      load_rows6(ib + 2 * CSTR, ra);
    }
    adder_ci4(rb, nw, acc);                          // compute cp+1
    ib += 2 * CSTR;
  }

  float* ob = out + ((size_t)(n * NCH + (cog << 2)) * PADH + (y + 1)) * PADW + (x0 + 1);
#pragma unroll
  for (int j = 0; j < 4; ++j)
#pragma unroll
    for (int p = 0; p < 4; ++p)
      ob[j * CSTR + p] = (float)acc[j][p] * QINV16;  // -sum|v-w|
}

// ---------------------------------------------------------------------------
// BN batch stats, 2-stage. Stage 1: 1024 blocks (channel x 8 slices), double
// partials. Stage 2: 1 block x 128, fixed-order -> deterministic.
__global__ __launch_bounds__(256) void bn_stats_part(
    const float* __restrict__ t, double* __restrict__ ps) {
  int c = blockIdx.x >> 3, sl = blockIdx.x & 7;
  int tid = threadIdx.x;
  double s = 0.0, s2 = 0.0;
  for (int i = tid; i < 4 * HW * HW; i += 256) {
    int nl = i / (HW * HW);
    int rem = i % (HW * HW);
    int r = rem / HW, x = rem % HW;
    int n = sl * 4 + nl;
    float v = t[((size_t)(n * NCH + c) * PADH + r + 1) * PADW + x + 1];
    s += v; s2 += (double)v * v;
  }
  __shared__ double sd[256], sq[256];
  sd[tid] = s; sq[tid] = s2;
  __syncthreads();
  for (int off = 128; off > 0; off >>= 1) {
    if (tid < off) { sd[tid] += sd[tid + off]; sq[tid] += sq[tid + off]; }
    __syncthreads();
  }
  if (tid == 0) {
    ps[(size_t)blockIdx.x * 2] = sd[0];
    ps[(size_t)blockIdx.x * 2 + 1] = sq[0];
  }
}

__global__ __launch_bounds__(128) void bn_finalize(
    const double* __restrict__ ps, const float* __restrict__ gamma,
    const float* __restrict__ beta, float* __restrict__ sb) {
  int c = threadIdx.x;                               // 0..127
  double s = 0.0, s2 = 0.0;
#pragma unroll
  for (int k = 0; k < 8; ++k) {
    s += ps[(size_t)(c * 8 + k) * 2];
    s2 += ps[(size_t)(c * 8 + k) * 2 + 1];
  }
  double cnt = (double)(NIMG * HW * HW);
  double mean = s / cnt;
  double var = s2 / cnt - mean * mean;
  double rstd = 1.0 / sqrt(var + 1e-5);
  double g = (double)gamma[c];
  sb[c] = (float)(g * rstd);
  sb[NCH + c] = (float)((double)beta[c] - mean * g * rstd);
}

// Final: out = relu(bn2(t5) + residual x), compact NCHW output.
__global__ __launch_bounds__(256) void final_kernel(
    const float* __restrict__ t5, const float* __restrict__ sb,
    const float* __restrict__ x, float* __restrict__ out) {
  int idx = blockIdx.x * 256 + threadIdx.x;          // 802816 float4 threads
  int f = idx * 4;
  int n = f / (NCH * HW * HW);
  int c = (f / (HW * HW)) % NCH;
  int o = f % (HW * HW);
  int y = o / HW, xc = o % HW;
  const float* tp = t5 + ((size_t)(n * NCH + c) * PADH + y + 1) * PADW + xc + 1;
  float sc = sb[c], bi = sb[NCH + c];
  float4 xv = *(const float4*)(x + f);
  float4 ov;
  ov.x = fmaxf(fmaf(tp[0], sc, bi) + xv.x, 0.0f);
  ov.y = fmaxf(fmaf(tp[1], sc, bi) + xv.y, 0.0f);
  ov.z = fmaxf(fmaf(tp[2], sc, bi) + xv.z, 0.0f);
  ov.w = fmaxf(fmaf(tp[3], sc, bi) + xv.w, 0.0f);
  *(float4*)(out + f) = ov;
}

// ---------------------------------------------------------------------------
extern "C" void kernel_launch(void* const* d_in, const int* in_sizes, int n_in,
                              void* d_out, int out_size, void* d_ws, size_t ws_size,
                              hipStream_t stream) {
  const float* x   = (const float*)d_in[0];
  const float* ws1 = (const float*)d_in[1];
  const float* wa1 = (const float*)d_in[2];
  const float* g1  = (const float*)d_in[3];
  const float* b1  = (const float*)d_in[4];
  const float* ws2 = (const float*)d_in[5];
  const float* wa2 = (const float*)d_in[6];
  const float* g2  = (const float*)d_in[7];
  const float* b2  = (const float*)d_in[8];
  float* out = (float*)d_out;

  float* w = (float*)d_ws;
  unsigned* P1 = (unsigned*)w;               // t1 / t4 (packed u16-pairs)
  float* P2 = w + PBUF;                      // t2 / t5 (fp32 padded)
  unsigned short* CL0 = (unsigned short*)(w + 2 * PBUF);  // x  bf16 k-minor
  unsigned short* CL1 = CL0 + PBUF;                       // t3 bf16 k-minor
  float* WAf = w + 3 * PBUF;                 // adder packed weights x2
  unsigned* WA = (unsigned*)WAf;
  unsigned short* WS = (unsigned short*)(WAf + 2 * (size_t)WREL);  // shift bf16 x2
  float* SB1 = WAf + 3 * (size_t)WREL;       // after WS (2*WREL ushorts)
  float* SB2 = SB1 + 256;
  double* PS = (double*)(SB2 + 256);         // 1024 x 2 doubles partials

  hipLaunchKernelGGL(prep_adder,      dim3(576),  dim3(256), 0, stream, wa1, wa2, WA);
  hipLaunchKernelGGL(prep_shift,      dim3(1152), dim3(256), 0, stream, ws1, ws2, WS);
  hipLaunchKernelGGL(pad_cl,          dim3(960),  dim3(256), 0, stream, x, CL0);
  hipLaunchKernelGGL(zero_halo,       dim3(960),  dim3(256), 0, stream, P1);
  hipLaunchKernelGGL(shift_mfma,      dim3(1568), dim3(512), 0, stream, CL0, WS, P1);            // t1
  hipLaunchKernelGGL(adder_conv,      dim3(1568), dim3(128), 0, stream, P1, WA, P2);             // t2
  hipLaunchKernelGGL(bn_stats_part,   dim3(1024), dim3(256), 0, stream, P2, PS);
  hipLaunchKernelGGL(bn_finalize,     dim3(1),    dim3(128), 0, stream, PS, g1, b1, SB1);
  hipLaunchKernelGGL(bn_apply_relu_cl,dim3(960),  dim3(256), 0, stream, P2, SB1, CL1);           // t3
  hipLaunchKernelGGL(shift_mfma,      dim3(1568), dim3(512), 0, stream, CL1, WS + WREL, P1);     // t4
  hipLaunchKernelGGL(adder_conv,      dim3(1568), dim3(128), 0, stream, P1, WA + WPACK, P2);     // t5
  hipLaunchKernelGGL(bn_stats_part,   dim3(1024), dim3(256), 0, stream, P2, PS);
  hipLaunchKernelGGL(bn_finalize,     dim3(1),    dim3(128), 0, stream, PS, g2, b2, SB2);
  hipLaunchKernelGGL(final_kernel,    dim3(3136), dim3(256), 0, stream, P2, SB2, x, out);
}

// Round 19
// 250.274 us; speedup vs baseline: 1.1910x; 1.1910x over previous
//
#include <hip/hip_runtime.h>

// Padded layouts (halos zero):
//   fp32 [N][C][30][32]        : adder OUTPUTS (t2/t5)
//   u32  [N][64][30][32]       : adder INPUTS (t1/t4), packed u16 ci-pairs,
//                                q = rn((v+8)*4096)
//   bf16 [n][yp30][kc4][xp32][ci32] : MFMA inputs (x, t3) -- k-block-minor so
//                                     every wave fragment load is 1KB contiguous
#define PADH 30
#define PADW 32
#define CSTR (PADH*PADW)            // 960 elems per channel(-pair)
#define NIMG 32
#define NCH  128
#define HW   28
#define PBUF ((size_t)NIMG*NCH*CSTR)   // 3,932,160
#define WREL (128*128*9)               // 147456 weights per tensor
#define WPACK (WREL/2)                 // 73728 packed u32 per adder tensor

#define QS16   4096.0f
#define QINV16 (-2.44140625e-04f)      // -1/4096 (adder output is negated sum)
#define QZERO16 0x80008000u            // packed pair of rn(8*4096)=32768

typedef __attribute__((ext_vector_type(8))) short bf16x8;
typedef __attribute__((ext_vector_type(4))) float f32x4;
typedef __attribute__((ext_vector_type(4))) unsigned u32x4;
// Constant-address-space view: block-uniform address -> compiler emits s_load
// into SGPRs (scalar pipe), not VMEM/LDS.
typedef __attribute__((address_space(4))) const u32x4 cu32x4;

__device__ __forceinline__ unsigned short f2bf(float f) {   // RNE
  unsigned u = __float_as_uint(f);
  return (unsigned short)((u + 0x7FFFu + ((u >> 16) & 1u)) >> 16);
}

// ---------------------------------------------------------------------------
// Adder weights -> [cog32][cipair(64)][tap(9)][co4] u32 packed u16 pairs.
__global__ __launch_bounds__(256) void prep_adder(
    const float* __restrict__ a1, const float* __restrict__ a2,
    unsigned* __restrict__ dst) {
  int gid = blockIdx.x * 256 + threadIdx.x;          // 2*73728 threads
  int t = gid / WPACK, r = gid % WPACK;
  const float* src = t ? a2 : a1;
  int co = r / 576;                                  // 64 pairs * 9 taps
  int rem = r % 576;
  int pair = rem / 9, tap = rem % 9;
  float v0 = src[co * 1152 + (2 * pair) * 9 + tap];
  float v1 = src[co * 1152 + (2 * pair + 1) * 9 + tap];
  unsigned q0 = __float2uint_rn((v0 + 8.0f) * QS16);
  unsigned q1 = __float2uint_rn((v1 + 8.0f) * QS16);
  int cog = co >> 2, j = co & 3;
  dst[(size_t)t * WPACK + (((cog * 64 + pair) * 9 + tap) << 2) + j] = q0 | (q1 << 16);
}

// Shift weights: quantize sign*2^round(log2|w|) (zero < 0.005), exact in bf16.
// Layout [cog8][tap9][kc4][co16][ci32]: wave A-frag = 1KB contiguous.
__global__ __launch_bounds__(256) void prep_shift(
    const float* __restrict__ s1, const float* __restrict__ s2,
    unsigned short* __restrict__ dst) {
  int gid = blockIdx.x * 256 + threadIdx.x;          // 2*147456 threads
  int t = gid / WREL, r = gid % WREL;
  float v = (t ? s2 : s1)[r];
  float aw = fabsf(v);
  if (aw < 0.005f) {
    v = 0.0f;
  } else {
    int e; float m = frexpf(aw, &e);
    int k = (m >= 0.70710678f) ? e : e - 1;          // round(log2 aw)
    v = ldexpf(copysignf(1.0f, v), k);               // exact power of two
  }
  int co = r / 1152, rem = r % 1152;
  int ci = rem / 9, tap = rem % 9;
  int cog = co >> 4, cop = co & 15;
  dst[(size_t)t * WREL +
      ((((size_t)(cog * 9 + tap) * 4 + (ci >> 5)) * 16 + cop) * 32 + (ci & 31))] = f2bf(v);
}

// ---------------------------------------------------------------------------
// x (compact NCHW fp32) -> bf16 padded [n][yp][kc4][xp32][ci32].
__global__ __launch_bounds__(256) void pad_cl(
    const float* __restrict__ x, unsigned short* __restrict__ o) {
  __shared__ unsigned short tile[32 * 130];
  int n = blockIdx.x / PADH, yp = blockIdx.x % PADH;
  int tid = threadIdx.x;
  bool rowok = (yp >= 1 && yp <= HW);
#pragma unroll
  for (int it = 0; it < 16; ++it) {
    int idx = it * 256 + tid;                        // xp fast -> coalesced read
    int ci = idx >> 5, xp = idx & 31;
    float v = 0.0f;
    if (rowok && xp >= 1 && xp <= HW)
      v = x[(size_t)(n * NCH + ci) * (HW * HW) + (yp - 1) * HW + (xp - 1)];
    tile[xp * 130 + ci] = f2bf(v);
  }
  __syncthreads();
  unsigned int* ob = (unsigned int*)(o + (size_t)(n * PADH + yp) * 4096);
#pragma unroll
  for (int it = 0; it < 8; ++it) {
    int uidx = it * 256 + tid;                       // [kc4][xp32][cp16] linear
    int kc = uidx >> 9, xp = (uidx >> 4) & 31, cp = uidx & 15;
    int ci = kc * 32 + 2 * cp;
    ob[uidx] = *(const unsigned int*)&tile[xp * 130 + ci];
  }
}

// t2 (fp32 padded) -> BN+ReLU -> bf16 padded [n][yp][kc4][xp32][ci32].
__global__ __launch_bounds__(256) void bn_apply_relu_cl(
    const float* __restrict__ t, const float* __restrict__ sb,
    unsigned short* __restrict__ o) {
  __shared__ unsigned short tile[32 * 130];
  int n = blockIdx.x / PADH, yp = blockIdx.x % PADH;
  int tid = threadIdx.x;
  bool rowok = (yp >= 1 && yp <= HW);
#pragma unroll
  for (int it = 0; it < 16; ++it) {
    int idx = it * 256 + tid;
    int ci = idx >> 5, xp = idx & 31;
    float v = 0.0f;
    if (rowok && xp >= 1 && xp <= HW) {
      float tv = t[((size_t)(n * NCH + ci) * PADH + yp) * PADW + xp];
      v = fmaxf(fmaf(tv, sb[ci], sb[NCH + ci]), 0.0f);
    }
    tile[xp * 130 + ci] = f2bf(v);
  }
  __syncthreads();
  unsigned int* ob = (unsigned int*)(o + (size_t)(n * PADH + yp) * 4096);
#pragma unroll
  for (int it = 0; it < 8; ++it) {
    int uidx = it * 256 + tid;
    int kc = uidx >> 9, xp = (uidx >> 4) & 31, cp = uidx & 15;
    int ci = kc * 32 + 2 * cp;
    ob[uidx] = *(const unsigned int*)&tile[xp * 130 + ci];
  }
}

// Zero (quantized) halo cells of the packed u32 adder-input buffer.
__global__ __launch_bounds__(256) void zero_halo(unsigned* __restrict__ b) {
  int gid = blockIdx.x * 256 + threadIdx.x;          // 2048*120 threads
  int nc = gid / 120, i = gid % 120;                 // nc over N*64 pairs
  unsigned* p = b + (size_t)nc * CSTR;
  if (i < 64) {
    int row = (i < 32) ? 0 : (PADH - 1);
    p[row * PADW + (i & 31)] = QZERO16;
  } else {
    int i2 = i - 64;
    int row = 1 + (i2 >> 1);
    int col = (i2 & 1) ? (HW + 1) : 0;
    p[row * PADW + col] = QZERO16;
  }
}

// ---------------------------------------------------------------------------
// Shift conv on matrix cores. Block = 512 thr = 8 waves = ALL 8 co-tiles of
// one (n, pxt): shared input tile (32KB) staged in LDS once, re-used by all
// 8 waves. Wave tap-fragment read = contiguous 1KB LDS -> conflict-free.
__global__ __launch_bounds__(512) void shift_mfma(
    const unsigned short* __restrict__ in, const unsigned short* __restrict__ wq,
    unsigned* __restrict__ out) {
  __shared__ uint4 btile4[2048];                     // 32KB: 4 rows x 8KB
  char* btile = (char*)btile4;
  int bid = blockIdx.x;
  int vb = (bid & 7) * 196 + (bid >> 3);             // bijective (1568 = 8*196)
  int pxt = vb % 49;
  int n = vb / 49;
  int cot = threadIdx.x >> 6;                        // wave id = co-tile 0..7
  int lane = threadIdx.x & 63;
  int t = threadIdx.x;

  int px0 = pxt * 16;
  int y0 = px0 / HW;                                 // logical row of first px
#pragma unroll
  for (int it = 0; it < 4; ++it) {
    int rp = y0 + it; if (rp > 29) rp = 29;
    const uint4* src = (const uint4*)(in + (size_t)(n * PADH + rp) * 4096) + t;
    *(uint4*)(btile + it * 8192 + t * 16) = *src;
  }
  __syncthreads();

  int px = px0 + (lane & 15);
  int y = px / HW, x = px % HW;
  int iro = y - y0;                                  // 0 or 1
  int colb = (x + 1) * 64 + (lane >> 4) * 16;        // byte offset in row blk
  const unsigned short* wbase =
      wq + (size_t)cot * 18432 + (lane & 15) * 32 + (lane >> 4) * 8;

  f32x4 acc = {0.f, 0.f, 0.f, 0.f};
#pragma unroll
  for (int tap = 0; tap < 9; ++tap) {
    const int ky = tap / 3 - 1, kx = tap % 3 - 1;
    const char* lb = btile + (iro + ky + 1) * 8192 + colb + kx * 64;
    const unsigned short* wb = wbase + tap * 2048;
#pragma unroll
    for (int kc = 0; kc < 4; ++kc) {
      bf16x8 a = *(const bf16x8*)(wb + kc * 512);
      bf16x8 b = *(const bf16x8*)(lb + kc * 2048);
      acc = __builtin_amdgcn_mfma_f32_16x16x32_bf16(a, b, acc, 0, 0, 0);
    }
  }
  int coa = cot * 16 + (lane >> 4) * 4;              // 4 consecutive co
  unsigned q[4];
#pragma unroll
  for (int r = 0; r < 4; ++r) {
    float v = fminf(fmaxf(acc[r], -7.9f), 7.9f);     // ~8-sigma clamp
    q[r] = __float2uint_rn((v + 8.0f) * QS16);
  }
  int cp = coa >> 1;                                 // channel-pair index
  unsigned* ob = out + ((size_t)(n * 64 + cp) * PADH + (y + 1)) * PADW + (x + 1);
  ob[0] = q[0] | (q[1] << 16);
  ob[CSTR] = q[2] | (q[3] << 16);
}

// ---------------------------------------------------------------------------
// AdderNet conv, packed u16 SAD (R16-winning config: 2px x 4co, 256 thr,
// dist-1 ping-pong, SGPR weights double-buffered). NEW: BN partial sums are
// fused into the epilogue (per-block 4-channel Sum/Sum2 via fixed-order
// shfl reduce + LDS combine) -- removes the standalone bn_stats_part pass.
__device__ __forceinline__ void sad16_op(unsigned& acc, unsigned vin, unsigned w) {
  asm("v_sad_u16 %0, %1, %2, %0" : "+v"(acc) : "v"(vin), "s"(w));
}

__device__ __forceinline__ void load_rows_u(const unsigned* __restrict__ p,
                                            unsigned r[3][4]) {
#pragma unroll
  for (int ky = 0; ky < 3; ++ky) {
    uint2 a = *(const uint2*)(p + ky * PADW);
    uint2 b = *(const uint2*)(p + ky * PADW + 2);
    r[ky][0] = a.x; r[ky][1] = a.y; r[ky][2] = b.x; r[ky][3] = b.y;
  }
}

__device__ __forceinline__ void adder_ci_reg(const unsigned r[3][4],
                                             const u32x4 w[9],
                                             unsigned acc[4][2]) {
#pragma unroll
  for (int ky = 0; ky < 3; ++ky)
#pragma unroll
    for (int kx = 0; kx < 3; ++kx) {
      u32x4 wA = w[ky * 3 + kx];                     // already in SGPRs
#pragma unroll
      for (int p = 0; p < 2; ++p) {
        unsigned v = r[ky][kx + p];
        sad16_op(acc[0][p], v, wA.x);
        sad16_op(acc[1][p], v, wA.y);
        sad16_op(acc[2][p], v, wA.z);
        sad16_op(acc[3][p], v, wA.w);
      }
    }
}

__global__ __launch_bounds__(256) void adder_conv(
    const unsigned* __restrict__ in, const unsigned* __restrict__ wr,
    float* __restrict__ out, double* __restrict__ ps) {
  int bid = blockIdx.x;
  int v = (bid & 7) * 196 + (bid >> 3);              // XCD remap (1568 = 8*196)
  int cog = v & 31;                                  // 32 groups of 4 co
  int chunk = v >> 5;                                // 0..48
  int tid = threadIdx.x;

  int wi = chunk * 256 + tid;                        // 0..12543
  int xh = wi % 14;
  int r2 = wi / 14;
  int y = r2 % 28;
  int n = r2 / 28;
  int x0 = xh << 1;
  const unsigned* ib = in + (size_t)n * 64 * CSTR + y * PADW + x0;  // ci-pair 0
  cu32x4* w4 = (cu32x4*)(wr + (size_t)cog * 2304);   // [cipair][9 x u32x4]

  unsigned acc[4][2];
#pragma unroll
  for (int j = 0; j < 4; ++j) { acc[j][0] = 0u; acc[j][1] = 0u; }

  u32x4 cw[9], nw[9];
#pragma unroll
  for (int t = 0; t < 9; ++t) cw[t] = w4[t];         // ci-pair 0 weights
  unsigned ra[3][4], rb[3][4];
  load_rows_u(ib, ra);

  for (int cp = 0; cp < 64; cp += 2) {
#pragma unroll
    for (int t = 0; t < 9; ++t) nw[t] = w4[(cp + 1) * 9 + t];   // prefetch cp+1
    load_rows_u(ib + CSTR, rb);
    adder_ci_reg(ra, cw, acc);                       // compute cp (uses cw)
    if (cp + 2 < 64) {
#pragma unroll
      for (int t = 0; t < 9; ++t) cw[t] = w4[(cp + 2) * 9 + t]; // prefetch cp+2
      load_rows_u(ib + 2 * CSTR, ra);
    }
    adder_ci_reg(rb, nw, acc);                       // compute cp+1 (uses nw)
    ib += 2 * CSTR;
  }

  float vout[4][2];
#pragma unroll
  for (int j = 0; j < 4; ++j) {
    vout[j][0] = (float)acc[j][0] * QINV16;          // -sum|v-w|
    vout[j][1] = (float)acc[j][1] * QINV16;
  }
  float* ob = out + ((size_t)(n * NCH + (cog << 2)) * PADH + (y + 1)) * PADW + (x0 + 1);
#pragma unroll
  for (int j = 0; j < 4; ++j) {
    ob[j * CSTR + 0] = vout[j][0];
    ob[j * CSTR + 1] = vout[j][1];
  }

  // Fused BN partials: per-block Sum/Sum2 for its 4 channels over 512 px.
  __shared__ double wred[4][8];                      // [wave][j*2+sel]
  int wv = tid >> 6, ln = tid & 63;
#pragma unroll
  for (int j = 0; j < 4; ++j) {
    double s  = (double)vout[j][0] + (double)vout[j][1];
    double s2 = (double)vout[j][0] * vout[j][0] + (double)vout[j][1] * vout[j][1];
#pragma unroll
    for (int off = 32; off > 0; off >>= 1) {
      s  += __shfl_down(s, off, 64);
      s2 += __shfl_down(s2, off, 64);
    }
    if (ln == 0) { wred[wv][j * 2] = s; wred[wv][j * 2 + 1] = s2; }
  }
  __syncthreads();
  if (tid == 0) {
#pragma unroll
    for (int j = 0; j < 4; ++j) {
      double S = 0.0, S2 = 0.0;
#pragma unroll
      for (int w8 = 0; w8 < 4; ++w8) { S += wred[w8][j * 2]; S2 += wred[w8][j * 2 + 1]; }
      ps[((size_t)(cog * 49 + chunk) * 4 + j) * 2]     = S;
      ps[((size_t)(cog * 49 + chunk) * 4 + j) * 2 + 1] = S2;
    }
  }
}

// ---------------------------------------------------------------------------
// BN finalize: per channel, fixed-order sum of its 49 chunk-partials ->
// deterministic. sb[c]=g*rstd, sb[128+c]=b-mean*g*rstd.
__global__ __launch_bounds__(128) void bn_finalize(
    const double* __restrict__ ps, const float* __restrict__ gamma,
    const float* __restrict__ beta, float* __restrict__ sb) {
  int c = threadIdx.x;                               // 0..127
  int cog = c >> 2, j = c & 3;
  double s = 0.0, s2 = 0.0;
  for (int ch = 0; ch < 49; ++ch) {
    s  += ps[((size_t)(cog * 49 + ch) * 4 + j) * 2];
    s2 += ps[((size_t)(cog * 49 + ch) * 4 + j) * 2 + 1];
  }
  double cnt = (double)(NIMG * HW * HW);
  double mean = s / cnt;
  double var = s2 / cnt - mean * mean;
  double rstd = 1.0 / sqrt(var + 1e-5);
  double g = (double)gamma[c];
  sb[c] = (float)(g * rstd);
  sb[NCH + c] = (float)((double)beta[c] - mean * g * rstd);
}

// Final: out = relu(bn2(t5) + residual x), compact NCHW output.
__global__ __launch_bounds__(256) void final_kernel(
    const float* __restrict__ t5, const float* __restrict__ sb,
    const float* __restrict__ x, float* __restrict__ out) {
  int idx = blockIdx.x * 256 + threadIdx.x;          // 802816 float4 threads
  int f = idx * 4;
  int n = f / (NCH * HW * HW);
  int c = (f / (HW * HW)) % NCH;
  int o = f % (HW * HW);
  int y = o / HW, xc = o % HW;
  const float* tp = t5 + ((size_t)(n * NCH + c) * PADH + y + 1) * PADW + xc + 1;
  float sc = sb[c], bi = sb[NCH + c];
  float4 xv = *(const float4*)(x + f);
  float4 ov;
  ov.x = fmaxf(fmaf(tp[0], sc, bi) + xv.x, 0.0f);
  ov.y = fmaxf(fmaf(tp[1], sc, bi) + xv.y, 0.0f);
  ov.z = fmaxf(fmaf(tp[2], sc, bi) + xv.z, 0.0f);
  ov.w = fmaxf(fmaf(tp[3], sc, bi) + xv.w, 0.0f);
  *(float4*)(out + f) = ov;
}

// ---------------------------------------------------------------------------
extern "C" void kernel_launch(void* const* d_in, const int* in_sizes, int n_in,
                              void* d_out, int out_size, void* d_ws, size_t ws_size,
                              hipStream_t stream) {
  const float* x   = (const float*)d_in[0];
  const float* ws1 = (const float*)d_in[1];
  const float* wa1 = (const float*)d_in[2];
  const float* g1  = (const float*)d_in[3];
  const float* b1  = (const float*)d_in[4];
  const float* ws2 = (const float*)d_in[5];
  const float* wa2 = (const float*)d_in[6];
  const float* g2  = (const float*)d_in[7];
  const float* b2  = (const float*)d_in[8];
  float* out = (float*)d_out;

  float* w = (float*)d_ws;
  unsigned* P1 = (unsigned*)w;               // t1 / t4 (packed u16-pairs)
  float* P2 = w + PBUF;                      // t2 / t5 (fp32 padded)
  unsigned short* CL0 = (unsigned short*)(w + 2 * PBUF);  // x  bf16 k-minor
  unsigned short* CL1 = CL0 + PBUF;                       // t3 bf16 k-minor
  float* WAf = w + 3 * PBUF;                 // adder packed weights x2
  unsigned* WA = (unsigned*)WAf;
  unsigned short* WS = (unsigned short*)(WAf + 2 * (size_t)WREL);  // shift bf16 x2
  float* SB1 = WAf + 3 * (size_t)WREL;       // after WS (2*WREL ushorts)
  float* SB2 = SB1 + 256;
  double* PS = (double*)(SB2 + 256);         // 1568 x 4 x 2 doubles partials

  hipLaunchKernelGGL(prep_adder,      dim3(576),  dim3(256), 0, stream, wa1, wa2, WA);
  hipLaunchKernelGGL(prep_shift,      dim3(1152), dim3(256), 0, stream, ws1, ws2, WS);
  hipLaunchKernelGGL(pad_cl,          dim3(960),  dim3(256), 0, stream, x, CL0);
  hipLaunchKernelGGL(zero_halo,       dim3(960),  dim3(256), 0, stream, P1);
  hipLaunchKernelGGL(shift_mfma,      dim3(1568), dim3(512), 0, stream, CL0, WS, P1);            // t1
  hipLaunchKernelGGL(adder_conv,      dim3(1568), dim3(256), 0, stream, P1, WA, P2, PS);         // t2 + BN1 partials
  hipLaunchKernelGGL(bn_finalize,     dim3(1),    dim3(128), 0, stream, PS, g1, b1, SB1);
  hipLaunchKernelGGL(bn_apply_relu_cl,dim3(960),  dim3(256), 0, stream, P2, SB1, CL1);           // t3
  hipLaunchKernelGGL(shift_mfma,      dim3(1568), dim3(512), 0, stream, CL1, WS + WREL, P1);     // t4
  hipLaunchKernelGGL(adder_conv,      dim3(1568), dim3(256), 0, stream, P1, WA + WPACK, P2, PS); // t5 + BN2 partials
  hipLaunchKernelGGL(bn_finalize,     dim3(1),    dim3(128), 0, stream, PS, g2, b2, SB2);
  hipLaunchKernelGGL(final_kernel,    dim3(3136), dim3(256), 0, stream, P2, SB2, x, out);
}